// Round 1
// baseline (60.754 us; speedup 1.0000x reference)
//
#include <hip/hip_runtime.h>
#include <math.h>

#define NPTS   2048
#define BATCH  32
#define M_POLY 815
#define SPLITS 8
#define CHUNK  256   // NPTS / SPLITS
#define TPW    48    // 3 dims * 16 Chebyshev orders per point

// ---------------------------------------------------------------------------
// Kernel 1: Chebyshev moment partial sums.
// grid = (SPLITS, BATCH), block = 256 threads.
// Each block: batch b, points [s*256, s*256+256). Each thread computes the
// T_0..T_15 table for its point (3 dims) into LDS, then accumulates <=4
// monomials over the 256 points. Writes partial sums to ws (deterministic).
// ---------------------------------------------------------------------------
__global__ __launch_bounds__(256) void moments_kernel(
    const float* __restrict__ x,      // (B, 3, N)
    const int*   __restrict__ exps,   // (M_POLY, 3)
    float*       __restrict__ part)   // (B, SPLITS, M_POLY)
{
    __shared__ float T[CHUNK * TPW];
    const int t = threadIdx.x;
    const int s = blockIdx.x;
    const int b = blockIdx.y;
    const int n = s * CHUNK + t;

    // Phase A: Chebyshev tables via recurrence T_k = 2x T_{k-1} - T_{k-2}
    const float* xb = x + (size_t)b * 3 * NPTS;
    #pragma unroll
    for (int j = 0; j < 3; ++j) {
        const float xv = xb[j * NPTS + n];
        float tm = 1.0f, tc = xv;
        float* dst = &T[t * TPW + j * 16];
        dst[0] = tm;
        dst[1] = tc;
        #pragma unroll
        for (int k = 2; k < 16; ++k) {
            const float tn = 2.0f * xv * tc - tm;
            dst[k] = tn;
            tm = tc; tc = tn;
        }
    }
    __syncthreads();

    // Phase B: each thread owns monomials m = t, t+256, t+512, t+768 (m<815)
    int off0[4], off1[4], off2[4];
    #pragma unroll
    for (int i = 0; i < 4; ++i) {
        const int m  = t + i * 256;
        const int mm = (m < M_POLY) ? m : 0;
        off0[i] = exps[mm * 3 + 0];
        off1[i] = 16 + exps[mm * 3 + 1];
        off2[i] = 32 + exps[mm * 3 + 2];
    }
    float acc[4] = {0.f, 0.f, 0.f, 0.f};
    for (int nn = 0; nn < CHUNK; ++nn) {
        const float* Tn = &T[nn * TPW];   // n uniform across wave -> broadcast-ish
        #pragma unroll
        for (int i = 0; i < 4; ++i) {
            acc[i] += Tn[off0[i]] * Tn[off1[i]] * Tn[off2[i]];
        }
    }

    float* pb = part + ((size_t)b * SPLITS + s) * M_POLY;
    #pragma unroll
    for (int i = 0; i < 4; ++i) {
        const int m = t + i * 256;
        if (m < M_POLY) pb[m] = acc[i];
    }
}

// ---------------------------------------------------------------------------
// Kernel 2: reduce partials (fold 1/N) + 4-layer MLP with BN(eval)+ReLU.
// grid = BATCH blocks, 512 threads. All inter-layer handoff in LDS.
// ---------------------------------------------------------------------------
__global__ __launch_bounds__(512) void mlp_kernel(
    const float* __restrict__ part,
    const float* __restrict__ W1, const float* __restrict__ b1,
    const float* __restrict__ g1, const float* __restrict__ be1,
    const float* __restrict__ rm1, const float* __restrict__ rv1,
    const float* __restrict__ W2, const float* __restrict__ b2,
    const float* __restrict__ g2, const float* __restrict__ be2,
    const float* __restrict__ rm2, const float* __restrict__ rv2,
    const float* __restrict__ W3, const float* __restrict__ b3,
    const float* __restrict__ g3, const float* __restrict__ be3,
    const float* __restrict__ rm3, const float* __restrict__ rv3,
    const float* __restrict__ W4, const float* __restrict__ b4,
    float* __restrict__ out)
{
    __shared__ float f[M_POLY];
    __shared__ float h1[512];
    __shared__ float h2[256];
    __shared__ float h3[128];
    const int t = threadIdx.x;
    const int b = blockIdx.x;
    const float invN = 1.0f / (float)NPTS;

    for (int m = t; m < M_POLY; m += 512) {
        float s = 0.f;
        #pragma unroll
        for (int sp = 0; sp < SPLITS; ++sp)
            s += part[((size_t)b * SPLITS + sp) * M_POLY + m];
        f[m] = s * invN;
    }
    __syncthreads();

    // layer 1: 815 -> 512
    {
        float dot = 0.f;
        for (int k = 0; k < M_POLY; ++k)
            dot = fmaf(f[k], W1[k * 512 + t], dot);
        const float v = (dot + b1[t] - rm1[t]) * g1[t] * rsqrtf(rv1[t] + 1e-5f) + be1[t];
        h1[t] = v > 0.f ? v : 0.f;
    }
    __syncthreads();

    // layer 2: 512 -> 256
    if (t < 256) {
        float dot = 0.f;
        for (int k = 0; k < 512; ++k)
            dot = fmaf(h1[k], W2[k * 256 + t], dot);
        const float v = (dot + b2[t] - rm2[t]) * g2[t] * rsqrtf(rv2[t] + 1e-5f) + be2[t];
        h2[t] = v > 0.f ? v : 0.f;
    }
    __syncthreads();

    // layer 3: 256 -> 128
    if (t < 128) {
        float dot = 0.f;
        for (int k = 0; k < 256; ++k)
            dot = fmaf(h2[k], W3[k * 128 + t], dot);
        const float v = (dot + b3[t] - rm3[t]) * g3[t] * rsqrtf(rv3[t] + 1e-5f) + be3[t];
        h3[t] = v > 0.f ? v : 0.f;
    }
    __syncthreads();

    // layer 4: 128 -> 40 (no BN/ReLU)
    if (t < 40) {
        float dot = 0.f;
        for (int k = 0; k < 128; ++k)
            dot = fmaf(h3[k], W4[k * 40 + t], dot);
        out[b * 40 + t] = dot + b4[t];
    }
}

extern "C" void kernel_launch(void* const* d_in, const int* in_sizes, int n_in,
                              void* d_out, int out_size, void* d_ws, size_t ws_size,
                              hipStream_t stream) {
    const float* x    = (const float*)d_in[0];
    const int*   exps = (const int*)d_in[1];
    const float* W1 = (const float*)d_in[2];
    const float* b1 = (const float*)d_in[3];
    const float* g1 = (const float*)d_in[4];
    const float* be1= (const float*)d_in[5];
    const float* rm1= (const float*)d_in[6];
    const float* rv1= (const float*)d_in[7];
    const float* W2 = (const float*)d_in[8];
    const float* b2 = (const float*)d_in[9];
    const float* g2 = (const float*)d_in[10];
    const float* be2= (const float*)d_in[11];
    const float* rm2= (const float*)d_in[12];
    const float* rv2= (const float*)d_in[13];
    const float* W3 = (const float*)d_in[14];
    const float* b3 = (const float*)d_in[15];
    const float* g3 = (const float*)d_in[16];
    const float* be3= (const float*)d_in[17];
    const float* rm3= (const float*)d_in[18];
    const float* rv3= (const float*)d_in[19];
    const float* W4 = (const float*)d_in[20];
    const float* b4 = (const float*)d_in[21];
    float* out  = (float*)d_out;
    float* part = (float*)d_ws;   // (B, SPLITS, M_POLY) floats = 834,560 B

    moments_kernel<<<dim3(SPLITS, BATCH), 256, 0, stream>>>(x, exps, part);
    mlp_kernel<<<BATCH, 512, 0, stream>>>(part,
        W1, b1, g1, be1, rm1, rv1,
        W2, b2, g2, be2, rm2, rv2,
        W3, b3, g3, be3, rm3, rv3,
        W4, b4, out);
}

// Round 2
// 40.330 us; speedup vs baseline: 1.5064x; 1.5064x over previous
//
#include <hip/hip_runtime.h>
#include <math.h>

#define NPTS   2048
#define BATCH  32
#define M_POLY 815
#define PG     64          // points per LDS group
#define PSTRIDE 153        // 136 pair products + 16 T2 + 1 pad (coprime w/ 32 banks)
#define BN_EPS 1e-5f

// ---------------------------------------------------------------------------
// Kernel 1: Chebyshev moment partial sums, pairwise-product formulation.
// grid = (NSPLIT, BATCH), block = 256. NSPLIT = 2048/(64*GPB).
// Per 64-point group: threads t<64 build, per point, the triangular table
// P01[i,j] = T_i(x0)*T_j(x1) (136 entries, register-computed, static-indexed)
// plus T2[16], into LDS. Then all 256 threads accumulate <=4 monomials each
// over the 64 points: 2 broadcast LDS reads + 1 FMA per monomial-point.
// ---------------------------------------------------------------------------
template<int GPB>
__global__ __launch_bounds__(256) void moments_kernel(
    const float* __restrict__ x,      // (B, 3, N)
    const int*   __restrict__ exps,   // (M_POLY, 3)
    float*       __restrict__ part)   // (B, NSPLIT, M_POLY)
{
    __shared__ float P[PG * PSTRIDE];  // 39,168 B
    const int t  = threadIdx.x;
    const int sb = blockIdx.x;
    const int b  = blockIdx.y;

    // monomial -> (pair index, T2 offset), 4 monomials per thread
    int off_p[4], off_t[4];
    #pragma unroll
    for (int i = 0; i < 4; ++i) {
        const int m  = t + i * 256;
        const int mm = (m < M_POLY) ? m : 0;
        const int e0 = exps[mm * 3 + 0];
        const int e1 = exps[mm * 3 + 1];
        const int e2 = exps[mm * 3 + 2];
        off_p[i] = (e0 * (33 - e0)) / 2 + e1;  // triangular row offset + col
        off_t[i] = 136 + e2;
    }

    float acc[4] = {0.f, 0.f, 0.f, 0.f};
    const float* xb = x + (size_t)b * 3 * NPTS;

    for (int g = 0; g < GPB; ++g) {
        __syncthreads();  // protect LDS reuse across groups
        if (t < PG) {
            const int n = (sb * GPB + g) * PG + t;
            float T[3][16];
            #pragma unroll
            for (int j = 0; j < 3; ++j) {
                const float xv = xb[j * NPTS + n];
                T[j][0] = 1.0f;
                T[j][1] = xv;
                #pragma unroll
                for (int k = 2; k < 16; ++k)
                    T[j][k] = 2.0f * xv * T[j][k - 1] - T[j][k - 2];
            }
            float* pt = &P[t * PSTRIDE];
            #pragma unroll
            for (int i = 0; i < 16; ++i) {
                const int rowoff = (i * (33 - i)) / 2;
                #pragma unroll
                for (int j = 0; j < 16 - i; ++j)
                    pt[rowoff + j] = T[0][i] * T[1][j];
            }
            #pragma unroll
            for (int k = 0; k < 16; ++k)
                pt[136 + k] = T[2][k];
        }
        __syncthreads();

        for (int nn = 0; nn < PG; ++nn) {
            const int base = nn * PSTRIDE;   // uniform across wave -> broadcast
            #pragma unroll
            for (int i = 0; i < 4; ++i)
                acc[i] = fmaf(P[base + off_p[i]], P[base + off_t[i]], acc[i]);
        }
    }

    const int nsplit = NPTS / (PG * GPB);
    float* pb = part + ((size_t)b * nsplit + sb) * M_POLY;
    #pragma unroll
    for (int i = 0; i < 4; ++i) {
        const int m = t + i * 256;
        if (m < M_POLY) pb[m] = acc[i];
    }
}

// ---------------------------------------------------------------------------
// Layer 1: reduce partials + 815->512 linear + BN + ReLU.
// grid = (8 out-groups, 32 batches), block 512. 8-way split-K (chains of 102).
// ---------------------------------------------------------------------------
__global__ __launch_bounds__(512) void l1_kernel(
    const float* __restrict__ part, int nsplit,
    const float* __restrict__ W1, const float* __restrict__ b1,
    const float* __restrict__ g1, const float* __restrict__ be1,
    const float* __restrict__ rm1, const float* __restrict__ rv1,
    float* __restrict__ h1)
{
    __shared__ float fs[816];
    __shared__ float red[8][64];
    const int t  = threadIdx.x;
    const int og = blockIdx.x;
    const int b  = blockIdx.y;
    const float invN = 1.0f / (float)NPTS;

    for (int m = t; m < M_POLY; m += 512) {
        float s = 0.f;
        for (int sp = 0; sp < nsplit; ++sp)
            s += part[((size_t)b * nsplit + sp) * M_POLY + m];
        fs[m] = s * invN;
    }
    if (t == 0) fs[815] = 0.f;
    __syncthreads();

    const int o  = og * 64 + (t & 63);
    const int c  = t >> 6;
    const int k0 = c * 102;            // 8*102 = 816; fs[815]=0 nulls the pad
    float acc = 0.f;
    #pragma unroll 6
    for (int k = k0; k < k0 + 102; ++k) {
        const int kr = (k < M_POLY) ? k : 0;
        acc = fmaf(fs[k], W1[kr * 512 + o], acc);
    }
    red[c][t & 63] = acc;
    __syncthreads();

    if (t < 64) {
        float dot = 0.f;
        #pragma unroll
        for (int j = 0; j < 8; ++j) dot += red[j][t];
        const int oo = og * 64 + t;
        const float v = (dot + b1[oo] - rm1[oo]) * g1[oo] * rsqrtf(rv1[oo] + BN_EPS) + be1[oo];
        h1[b * 512 + oo] = v > 0.f ? v : 0.f;
    }
}

// ---------------------------------------------------------------------------
// Layer 2: 512->256 linear + BN + ReLU. grid = (4, 32), block 512, 8-way K.
// ---------------------------------------------------------------------------
__global__ __launch_bounds__(512) void l2_kernel(
    const float* __restrict__ h1,
    const float* __restrict__ W2, const float* __restrict__ b2,
    const float* __restrict__ g2, const float* __restrict__ be2,
    const float* __restrict__ rm2, const float* __restrict__ rv2,
    float* __restrict__ h2)
{
    __shared__ float hs[512];
    __shared__ float red[8][64];
    const int t  = threadIdx.x;
    const int og = blockIdx.x;
    const int b  = blockIdx.y;

    hs[t] = h1[b * 512 + t];
    __syncthreads();

    const int o  = og * 64 + (t & 63);
    const int c  = t >> 6;
    const int k0 = c * 64;
    float acc = 0.f;
    #pragma unroll 8
    for (int k = k0; k < k0 + 64; ++k)
        acc = fmaf(hs[k], W2[k * 256 + o], acc);
    red[c][t & 63] = acc;
    __syncthreads();

    if (t < 64) {
        float dot = 0.f;
        #pragma unroll
        for (int j = 0; j < 8; ++j) dot += red[j][t];
        const int oo = og * 64 + t;
        const float v = (dot + b2[oo] - rm2[oo]) * g2[oo] * rsqrtf(rv2[oo] + BN_EPS) + be2[oo];
        h2[b * 256 + oo] = v > 0.f ? v : 0.f;
    }
}

// ---------------------------------------------------------------------------
// Layers 3+4 fused: 256->128 (BN+ReLU) -> 128->40. grid = 32, block 512.
// ---------------------------------------------------------------------------
__global__ __launch_bounds__(512) void l34_kernel(
    const float* __restrict__ h2,
    const float* __restrict__ W3, const float* __restrict__ b3,
    const float* __restrict__ g3, const float* __restrict__ be3,
    const float* __restrict__ rm3, const float* __restrict__ rv3,
    const float* __restrict__ W4, const float* __restrict__ b4,
    float* __restrict__ out)
{
    __shared__ float hs[256];
    __shared__ float red3[4][128];
    __shared__ float h3s[128];
    __shared__ float red4[8][64];
    const int t = threadIdx.x;
    const int b = blockIdx.x;

    if (t < 256) hs[t] = h2[b * 256 + t];
    __syncthreads();

    // layer 3: o = t&127, 4-way K split (64 each)
    {
        const int o  = t & 127;
        const int c  = t >> 7;
        const int k0 = c * 64;
        float acc = 0.f;
        #pragma unroll 8
        for (int k = k0; k < k0 + 64; ++k)
            acc = fmaf(hs[k], W3[k * 128 + o], acc);
        red3[c][o] = acc;
    }
    __syncthreads();
    if (t < 128) {
        float dot = red3[0][t] + red3[1][t] + red3[2][t] + red3[3][t];
        const float v = (dot + b3[t] - rm3[t]) * g3[t] * rsqrtf(rv3[t] + BN_EPS) + be3[t];
        h3s[t] = v > 0.f ? v : 0.f;
    }
    __syncthreads();

    // layer 4: o = t&63 (valid < 40), 8-way K split (16 each)
    {
        const int o  = t & 63;
        const int om = (o < 40) ? o : 39;   // clamp loads, discard result
        const int c  = t >> 6;
        const int k0 = c * 16;
        float acc = 0.f;
        #pragma unroll
        for (int k = k0; k < k0 + 16; ++k)
            acc = fmaf(h3s[k], W4[k * 40 + om], acc);
        red4[c][o] = acc;
    }
    __syncthreads();
    if (t < 40) {
        float dot = 0.f;
        #pragma unroll
        for (int j = 0; j < 8; ++j) dot += red4[j][t];
        out[b * 40 + t] = dot + b4[t];
    }
}

extern "C" void kernel_launch(void* const* d_in, const int* in_sizes, int n_in,
                              void* d_out, int out_size, void* d_ws, size_t ws_size,
                              hipStream_t stream) {
    const float* x    = (const float*)d_in[0];
    const int*   exps = (const int*)d_in[1];
    const float* W1 = (const float*)d_in[2];
    const float* b1 = (const float*)d_in[3];
    const float* g1 = (const float*)d_in[4];
    const float* be1= (const float*)d_in[5];
    const float* rm1= (const float*)d_in[6];
    const float* rv1= (const float*)d_in[7];
    const float* W2 = (const float*)d_in[8];
    const float* b2 = (const float*)d_in[9];
    const float* g2 = (const float*)d_in[10];
    const float* be2= (const float*)d_in[11];
    const float* rm2= (const float*)d_in[12];
    const float* rv2= (const float*)d_in[13];
    const float* W3 = (const float*)d_in[14];
    const float* b3 = (const float*)d_in[15];
    const float* g3 = (const float*)d_in[16];
    const float* be3= (const float*)d_in[17];
    const float* rm3= (const float*)d_in[18];
    const float* rv3= (const float*)d_in[19];
    const float* W4 = (const float*)d_in[20];
    const float* b4 = (const float*)d_in[21];
    float* out = (float*)d_out;

    // workspace layout: part (B*nsplit*815) | h1 (32*512) | h2 (32*256)
    const size_t hElems = (size_t)BATCH * 512 + (size_t)BATCH * 256;
    int nsplit, gpb;
    if (ws_size >= ((size_t)BATCH * 16 * M_POLY + hElems) * 4)      { nsplit = 16; gpb = 2; }
    else if (ws_size >= ((size_t)BATCH * 8 * M_POLY + hElems) * 4)  { nsplit = 8;  gpb = 4; }
    else                                                            { nsplit = 4;  gpb = 8; }

    float* part = (float*)d_ws;
    float* h1   = part + (size_t)BATCH * nsplit * M_POLY;
    float* h2   = h1 + (size_t)BATCH * 512;

    if (gpb == 2)
        moments_kernel<2><<<dim3(16, BATCH), 256, 0, stream>>>(x, exps, part);
    else if (gpb == 4)
        moments_kernel<4><<<dim3(8, BATCH), 256, 0, stream>>>(x, exps, part);
    else
        moments_kernel<8><<<dim3(4, BATCH), 256, 0, stream>>>(x, exps, part);

    l1_kernel<<<dim3(8, BATCH), 512, 0, stream>>>(part, nsplit,
        W1, b1, g1, be1, rm1, rv1, h1);
    l2_kernel<<<dim3(4, BATCH), 512, 0, stream>>>(h1,
        W2, b2, g2, be2, rm2, rv2, h2);
    l34_kernel<<<BATCH, 512, 0, stream>>>(h2,
        W3, b3, g3, be3, rm3, rv3, W4, b4, out);
}